// Round 14
// baseline (67.001 us; speedup 1.0000x reference)
//
#include <hip/hip_runtime.h>
#include <math.h>

#define NB 16
#define CB 256
#define MIP 8
#define EPSV 1e-5f

// ---- shared plane helpers (uniform-branch safe: __syncthreads inside) ----

__device__ __forceinline__ void reduce_plane(
    const float* __restrict__ x, const float* __restrict__ res,
    float* __restrict__ xh, float* __restrict__ xw,
    int plane, int t, float* spad)
{
    const float4* px4 = (const float4*)(x   + (size_t)plane * 4096);
    const float4* pr4 = (const float4*)(res + (size_t)plane * 4096);
    float4 a[4], b[4];
#pragma unroll
    for (int i = 0; i < 4; i++) a[i] = px4[i * 256 + t];
#pragma unroll
    for (int i = 0; i < 4; i++) b[i] = pr4[i * 256 + t];
    float cs0 = 0.f, cs1 = 0.f, cs2 = 0.f, cs3 = 0.f;
    float rsum[4];
#pragma unroll
    for (int i = 0; i < 4; i++) {
        float s0 = a[i].x + b[i].x, s1 = a[i].y + b[i].y;
        float s2 = a[i].z + b[i].z, s3 = a[i].w + b[i].w;
        cs0 += s0; cs1 += s1; cs2 += s2; cs3 += s3;
        rsum[i] = (s0 + s1) + (s2 + s3);
    }
#pragma unroll
    for (int i = 0; i < 4; i++) {
        float rs = rsum[i];
        rs += __shfl_xor(rs, 1);
        rs += __shfl_xor(rs, 2);
        rs += __shfl_xor(rs, 4);
        rs += __shfl_xor(rs, 8);
        rsum[i] = rs;
    }
    if ((t & 15) == 0) {
        int g = t >> 4;
#pragma unroll
        for (int i = 0; i < 4; i++)
            xh[(size_t)plane * 64 + i * 16 + g] = rsum[i] * 0.015625f;
    }
    cs0 += __shfl_xor(cs0, 16); cs0 += __shfl_xor(cs0, 32);
    cs1 += __shfl_xor(cs1, 16); cs1 += __shfl_xor(cs1, 32);
    cs2 += __shfl_xor(cs2, 16); cs2 += __shfl_xor(cs2, 32);
    cs3 += __shfl_xor(cs3, 16); cs3 += __shfl_xor(cs3, 32);
    int wv = t >> 6;
    int j  = t & 15;
    if ((t & 63) < 16) {
        float* d = &spad[wv * 64 + j * 4];
        d[0] = cs0; d[1] = cs1; d[2] = cs2; d[3] = cs3;
    }
    __syncthreads();
    if (t < 64)
        xw[(size_t)plane * 64 + t] =
            (spad[t] + spad[64 + t] + spad[128 + t] + spad[192 + t]) * 0.015625f;
}

__device__ __forceinline__ void apply_plane(
    const float* __restrict__ x, const float* __restrict__ res,
    const float* __restrict__ ah, const float* __restrict__ aw,
    float* __restrict__ out, int plane, int t, float* sah, float* saw)
{
    const float4* px4 = (const float4*)(x   + (size_t)plane * 4096);
    const float4* pr4 = (const float4*)(res + (size_t)plane * 4096);
    float4*       po4 = (float4*)(out + (size_t)plane * 4096);
    if (t < 64)       sah[t]      = ah[(size_t)plane * 64 + t];
    else if (t < 128) saw[t - 64] = aw[(size_t)plane * 64 + (t - 64)];
    __syncthreads();
    const float4 sw4 = *(const float4*)&saw[4 * (t & 15)];
#pragma unroll
    for (int i = 0; i < 4; i++) {
        int row = i * 16 + (t >> 4);
        float ahr2 = 2.f * sah[row];
        float4 a = px4[i * 256 + t];
        float4 b = pr4[i * 256 + t];
        float4 oo;
        oo.x = a.x * (ahr2 * sw4.x) + 2.f * b.x;
        oo.y = a.y * (ahr2 * sw4.y) + 2.f * b.y;
        oo.z = a.z * (ahr2 * sw4.z) + 2.f * b.z;
        oo.w = a.w * (ahr2 * sw4.w) + 2.f * b.w;
        po4[i * 256 + t] = oo;
    }
}

// ---- K1: reduce 8 images (2048 planes), zig-zag descending within XCD ----
__global__ __launch_bounds__(256) void k_reduce_half(
    const float* __restrict__ x, const float* __restrict__ res,
    float* __restrict__ xh, float* __restrict__ xw, int img0)
{
    __shared__ float spad[256];
    int bid = blockIdx.x;                           // 0..2047
    int pl  = (bid & 7) + 8 * (255 - (bid >> 3));   // same XCD, reversed
    reduce_plane(x, res, xh, xw, img0 * CB + pl, threadIdx.x, spad);
}

// ---- K2: mid for 8 images; grid 64 (8 images x 8 p-chunks) ----
__global__ __launch_bounds__(256) void k_mid_half(
    const float* __restrict__ xh, const float* __restrict__ xw,
    const float* __restrict__ w1, const float* __restrict__ b1,
    const float* __restrict__ gamma, const float* __restrict__ beta,
    const float* __restrict__ mean, const float* __restrict__ var,
    const float* __restrict__ w2, const float* __restrict__ b2,
    const float* __restrict__ w3, const float* __restrict__ b3,
    float* __restrict__ ah, float* __restrict__ aw, int img0)
{
    int n  = img0 + (blockIdx.x >> 3);
    int pc = blockIdx.x & 7;
    int t  = threadIdx.x;
    int ph = t & 15;
    int p  = pc * 16 + ph;
    int m  = (t >> 4) & 7;
    int half = t >> 7;
    __shared__ float part[256];
    __shared__ float ylds[MIP * 16];

    const float* pool = (p < 64) ? (xh + ((size_t)n * CB) * 64 + p)
                                 : (xw + ((size_t)n * CB) * 64 + (p - 64));
    float acc = 0.f;
    int c0 = half * 128;
#pragma unroll 16
    for (int ci = 0; ci < 128; ci++) {
        int c = c0 + ci;
        acc += pool[(size_t)c * 64] * w1[m * CB + c];
    }
    part[t] = acc;
    __syncthreads();
    if (t < 128) {
        float val = part[t] + part[t + 128] + b1[m];
        float inv = gamma[m] * rsqrtf(var[m] + EPSV);
        val = (val - mean[m]) * inv + beta[m];
        float cl = fminf(fmaxf(val + 3.f, 0.f), 6.f);
        ylds[m * 16 + ph] = val * cl * (1.f / 6.f);
    }
    __syncthreads();
    const float* wsel = (p < 64) ? w2 : w3;
    const float* bsel = (p < 64) ? b2 : b3;
    float* osel = (p < 64) ? (ah + ((size_t)n * CB) * 64 + p)
                           : (aw + ((size_t)n * CB) * 64 + (p - 64));
#pragma unroll
    for (int oo = 0; oo < 16; oo++) {
        int o = oo * 16 + (t >> 4);
        float acc2 = bsel[o];
#pragma unroll
        for (int mm = 0; mm < MIP; mm++)
            acc2 += wsel[o * MIP + mm] * ylds[mm * 16 + ph];
        osel[(size_t)o * 64] = 1.f / (1.f + __expf(-acc2));
    }
}

// ---- K3: FUSED — R(img0_r..+7) overlapped with A(img0_a..+7) ----
// Blocks alternate in groups of 8 so both types round-robin all XCDs:
// type = (bid>>3)&1, idx = (bid&7) + ((bid>>4)<<3) in [0,2048).
__global__ __launch_bounds__(256) void k_fused_ra(
    const float* __restrict__ x, const float* __restrict__ res,
    float* __restrict__ xh, float* __restrict__ xw,
    const float* __restrict__ ah, const float* __restrict__ aw,
    float* __restrict__ out, int img0_r, int img0_a)
{
    __shared__ float spad[256];
    __shared__ float sah[64], saw[64];
    int bid  = blockIdx.x;
    int type = (bid >> 3) & 1;
    int idx  = (bid & 7) + ((bid >> 4) << 3);
    int t    = threadIdx.x;
    if (type == 0) {
        int pl = (idx & 7) + 8 * (255 - (idx >> 3));   // zig-zag descending
        reduce_plane(x, res, xh, xw, img0_r * CB + pl, t, spad);
    } else {
        apply_plane(x, res, ah, aw, out, img0_a * CB + idx, t, sah, saw);
    }
}

// ---- K4: apply 8 images, ascending ----
__global__ __launch_bounds__(256) void k_apply_half(
    const float* __restrict__ x, const float* __restrict__ res,
    const float* __restrict__ ah, const float* __restrict__ aw,
    float* __restrict__ out, int img0)
{
    __shared__ float sah[64], saw[64];
    apply_plane(x, res, ah, aw, out, img0 * CB + blockIdx.x, threadIdx.x,
                sah, saw);
}

extern "C" void kernel_launch(void* const* d_in, const int* in_sizes, int n_in,
                              void* d_out, int out_size, void* d_ws, size_t ws_size,
                              hipStream_t stream) {
    const float* x     = (const float*)d_in[0];
    const float* res   = (const float*)d_in[1];
    const float* w1    = (const float*)d_in[2];
    const float* b1    = (const float*)d_in[3];
    const float* gamma = (const float*)d_in[4];
    const float* beta  = (const float*)d_in[5];
    const float* mean  = (const float*)d_in[6];
    const float* var   = (const float*)d_in[7];
    const float* w2    = (const float*)d_in[8];
    const float* b2    = (const float*)d_in[9];
    const float* w3    = (const float*)d_in[10];
    const float* b3    = (const float*)d_in[11];
    float* out = (float*)d_out;

    float* ws = (float*)d_ws;
    float* xh = ws;                 // 4096 planes * 64
    float* xw = ws + 262144;
    float* ah = ws + 524288;
    float* aw = ws + 786432;        // total 4 MiB

    // R(0-7); mid(0-7); [R(8-15) || A(0-7)]; mid(8-15); A(8-15)
    k_reduce_half<<<2048, 256, 0, stream>>>(x, res, xh, xw, 0);
    k_mid_half<<<64, 256, 0, stream>>>(xh, xw, w1, b1, gamma, beta, mean, var,
                                       w2, b2, w3, b3, ah, aw, 0);
    k_fused_ra<<<4096, 256, 0, stream>>>(x, res, xh, xw, ah, aw, out, 8, 0);
    k_mid_half<<<64, 256, 0, stream>>>(xh, xw, w1, b1, gamma, beta, mean, var,
                                       w2, b2, w3, b3, ah, aw, 8);
    k_apply_half<<<2048, 256, 0, stream>>>(x, res, ah, aw, out, 8);
}

// Round 15
// 60.425 us; speedup vs baseline: 1.1088x; 1.1088x over previous
//
#include <hip/hip_runtime.h>
#include <math.h>

#define NB 16
#define CB 256
#define MIP 8
#define EPSV 1e-5f

// K1: 2048 persistent-resident blocks (8/CU = 32 waves/CU), 2 planes each,
// zig-zag descending within XCD. Second plane's loads issue before first
// plane's epilogue -> deeper per-CU miss pipeline.
__global__ __launch_bounds__(256, 8) void k_reduce(const float* __restrict__ x,
                                                   const float* __restrict__ res,
                                                   float* __restrict__ xh,
                                                   float* __restrict__ xw) {
    int bid = blockIdx.x;
    int t   = threadIdx.x;
    int xcd = bid & 7;
    int g   = bid >> 3;                       // 0..255
    int p0  = xcd + 8 * (511 - 2 * g);        // descending within XCD
    int p1  = p0 - 8;
    const float4* px0 = (const float4*)(x   + (size_t)p0 * 4096);
    const float4* pr0 = (const float4*)(res + (size_t)p0 * 4096);
    const float4* px1 = (const float4*)(x   + (size_t)p1 * 4096);
    const float4* pr1 = (const float4*)(res + (size_t)p1 * 4096);
    __shared__ float spadA[256], spadB[256];
    int wv = t >> 6, j = t & 15;

    // ---- plane p0: loads ----
    float4 a[4], b[4];
#pragma unroll
    for (int i = 0; i < 4; i++) a[i] = px0[i * 256 + t];
#pragma unroll
    for (int i = 0; i < 4; i++) b[i] = pr0[i * 256 + t];

    float cs0 = 0.f, cs1 = 0.f, cs2 = 0.f, cs3 = 0.f;
    float rsum[4];
#pragma unroll
    for (int i = 0; i < 4; i++) {
        float s0 = a[i].x + b[i].x, s1 = a[i].y + b[i].y;
        float s2 = a[i].z + b[i].z, s3 = a[i].w + b[i].w;
        cs0 += s0; cs1 += s1; cs2 += s2; cs3 += s3;
        rsum[i] = (s0 + s1) + (s2 + s3);
    }

    // ---- plane p1: issue loads now (in flight through p0's epilogue) ----
    float4 c[4], d[4];
#pragma unroll
    for (int i = 0; i < 4; i++) c[i] = px1[i * 256 + t];
#pragma unroll
    for (int i = 0; i < 4; i++) d[i] = pr1[i * 256 + t];

    // ---- p0 epilogue ----
#pragma unroll
    for (int i = 0; i < 4; i++) {
        float rs = rsum[i];
        rs += __shfl_xor(rs, 1);
        rs += __shfl_xor(rs, 2);
        rs += __shfl_xor(rs, 4);
        rs += __shfl_xor(rs, 8);
        rsum[i] = rs;
    }
    if ((t & 15) == 0) {
        int gg = t >> 4;
#pragma unroll
        for (int i = 0; i < 4; i++)
            xh[(size_t)p0 * 64 + i * 16 + gg] = rsum[i] * 0.015625f;
    }
    cs0 += __shfl_xor(cs0, 16); cs0 += __shfl_xor(cs0, 32);
    cs1 += __shfl_xor(cs1, 16); cs1 += __shfl_xor(cs1, 32);
    cs2 += __shfl_xor(cs2, 16); cs2 += __shfl_xor(cs2, 32);
    cs3 += __shfl_xor(cs3, 16); cs3 += __shfl_xor(cs3, 32);
    if ((t & 63) < 16) {
        float* dd = &spadA[wv * 64 + j * 4];
        dd[0] = cs0; dd[1] = cs1; dd[2] = cs2; dd[3] = cs3;
    }
    __syncthreads();
    if (t < 64)
        xw[(size_t)p0 * 64 + t] =
            (spadA[t] + spadA[64 + t] + spadA[128 + t] + spadA[192 + t]) * 0.015625f;

    // ---- plane p1 ----
    float es0 = 0.f, es1 = 0.f, es2 = 0.f, es3 = 0.f;
    float rsum2[4];
#pragma unroll
    for (int i = 0; i < 4; i++) {
        float s0 = c[i].x + d[i].x, s1 = c[i].y + d[i].y;
        float s2 = c[i].z + d[i].z, s3 = c[i].w + d[i].w;
        es0 += s0; es1 += s1; es2 += s2; es3 += s3;
        rsum2[i] = (s0 + s1) + (s2 + s3);
    }
#pragma unroll
    for (int i = 0; i < 4; i++) {
        float rs = rsum2[i];
        rs += __shfl_xor(rs, 1);
        rs += __shfl_xor(rs, 2);
        rs += __shfl_xor(rs, 4);
        rs += __shfl_xor(rs, 8);
        rsum2[i] = rs;
    }
    if ((t & 15) == 0) {
        int gg = t >> 4;
#pragma unroll
        for (int i = 0; i < 4; i++)
            xh[(size_t)p1 * 64 + i * 16 + gg] = rsum2[i] * 0.015625f;
    }
    es0 += __shfl_xor(es0, 16); es0 += __shfl_xor(es0, 32);
    es1 += __shfl_xor(es1, 16); es1 += __shfl_xor(es1, 32);
    es2 += __shfl_xor(es2, 16); es2 += __shfl_xor(es2, 32);
    es3 += __shfl_xor(es3, 16); es3 += __shfl_xor(es3, 32);
    if ((t & 63) < 16) {
        float* dd = &spadB[wv * 64 + j * 4];
        dd[0] = es0; dd[1] = es1; dd[2] = es2; dd[3] = es3;
    }
    __syncthreads();
    if (t < 64)
        xw[(size_t)p1 * 64 + t] =
            (spadB[t] + spadB[64 + t] + spadB[128 + t] + spadB[192 + t]) * 0.015625f;
}

// K2: grid = NB*8 blocks. Block (n, pc) covers p in [pc*16, pc*16+16).
__global__ __launch_bounds__(256) void k_mid(const float* __restrict__ xh,
                                             const float* __restrict__ xw,
                                             const float* __restrict__ w1,
                                             const float* __restrict__ b1,
                                             const float* __restrict__ gamma,
                                             const float* __restrict__ beta,
                                             const float* __restrict__ mean,
                                             const float* __restrict__ var,
                                             const float* __restrict__ w2,
                                             const float* __restrict__ b2,
                                             const float* __restrict__ w3,
                                             const float* __restrict__ b3,
                                             float* __restrict__ ah,
                                             float* __restrict__ aw) {
    int n  = blockIdx.x >> 3;
    int pc = blockIdx.x & 7;
    int t  = threadIdx.x;
    int ph = t & 15;
    int p  = pc * 16 + ph;
    int m  = (t >> 4) & 7;
    int half = t >> 7;
    __shared__ float part[256];
    __shared__ float ylds[MIP * 16];

    const float* pool = (p < 64) ? (xh + ((size_t)n * CB) * 64 + p)
                                 : (xw + ((size_t)n * CB) * 64 + (p - 64));
    float acc = 0.f;
    int c0 = half * 128;
#pragma unroll 16
    for (int ci = 0; ci < 128; ci++) {
        int c = c0 + ci;
        acc += pool[(size_t)c * 64] * w1[m * CB + c];
    }
    part[t] = acc;
    __syncthreads();
    if (t < 128) {
        float val = part[t] + part[t + 128] + b1[m];
        float inv = gamma[m] * rsqrtf(var[m] + EPSV);
        val = (val - mean[m]) * inv + beta[m];
        float cl = fminf(fmaxf(val + 3.f, 0.f), 6.f);
        ylds[m * 16 + ph] = val * cl * (1.f / 6.f);
    }
    __syncthreads();
    const float* wsel = (p < 64) ? w2 : w3;
    const float* bsel = (p < 64) ? b2 : b3;
    float* osel = (p < 64) ? (ah + ((size_t)n * CB) * 64 + p)
                           : (aw + ((size_t)n * CB) * 64 + (p - 64));
#pragma unroll
    for (int oo = 0; oo < 16; oo++) {
        int o = oo * 16 + (t >> 4);
        float acc2 = bsel[o];
#pragma unroll
        for (int mm = 0; mm < MIP; mm++)
            acc2 += wsel[o * MIP + mm] * ylds[mm * 16 + ph];
        osel[(size_t)o * 64] = 1.f / (1.f + __expf(-acc2));
    }
}

// K3: per (n,o) plane: load ah/aw, out = 2*wei*x + 2*res.  Ascending order
// (head reads k_reduce's L2/L3-hot tail).
__global__ __launch_bounds__(256) void k_apply(const float* __restrict__ x,
                                               const float* __restrict__ res,
                                               const float* __restrict__ ah,
                                               const float* __restrict__ aw,
                                               float* __restrict__ out) {
    int plane = blockIdx.x;
    const float4* px4 = (const float4*)(x   + (size_t)plane * 4096);
    const float4* pr4 = (const float4*)(res + (size_t)plane * 4096);
    float4*       po4 = (float4*)(out + (size_t)plane * 4096);
    __shared__ float sah[64], saw[64];
    int t = threadIdx.x;
    if (t < 64)       sah[t]      = ah[(size_t)plane * 64 + t];
    else if (t < 128) saw[t - 64] = aw[(size_t)plane * 64 + (t - 64)];
    __syncthreads();
    const float4 sw4 = *(const float4*)&saw[4 * (t & 15)];
#pragma unroll
    for (int i = 0; i < 4; i++) {
        int row = i * 16 + (t >> 4);
        float ahr2 = 2.f * sah[row];
        float4 a = px4[i * 256 + t];
        float4 b = pr4[i * 256 + t];
        float4 oo;
        oo.x = a.x * (ahr2 * sw4.x) + 2.f * b.x;
        oo.y = a.y * (ahr2 * sw4.y) + 2.f * b.y;
        oo.z = a.z * (ahr2 * sw4.z) + 2.f * b.z;
        oo.w = a.w * (ahr2 * sw4.w) + 2.f * b.w;
        po4[i * 256 + t] = oo;
    }
}

extern "C" void kernel_launch(void* const* d_in, const int* in_sizes, int n_in,
                              void* d_out, int out_size, void* d_ws, size_t ws_size,
                              hipStream_t stream) {
    const float* x     = (const float*)d_in[0];
    const float* res   = (const float*)d_in[1];
    const float* w1    = (const float*)d_in[2];
    const float* b1    = (const float*)d_in[3];
    const float* gamma = (const float*)d_in[4];
    const float* beta  = (const float*)d_in[5];
    const float* mean  = (const float*)d_in[6];
    const float* var   = (const float*)d_in[7];
    const float* w2    = (const float*)d_in[8];
    const float* b2    = (const float*)d_in[9];
    const float* w3    = (const float*)d_in[10];
    const float* b3    = (const float*)d_in[11];
    float* out = (float*)d_out;

    float* ws = (float*)d_ws;
    float* xh = ws;                 // 16*256*64 = 262144 floats
    float* xw = ws + 262144;
    float* ah = ws + 524288;
    float* aw = ws + 786432;        // total 4 MiB

    k_reduce<<<2048, 256, 0, stream>>>(x, res, xh, xw);
    k_mid<<<NB * 8, 256, 0, stream>>>(xh, xw, w1, b1, gamma, beta, mean, var,
                                      w2, b2, w3, b3, ah, aw);
    k_apply<<<NB * CB, 256, 0, stream>>>(x, res, ah, aw, out);
}

// Round 16
// 57.549 us; speedup vs baseline: 1.1642x; 1.0500x over previous
//
#include <hip/hip_runtime.h>
#include <math.h>

#define NB 16
#define CB 256
#define MIP 8
#define EPSV 1e-5f

// K1: per (n,c) plane: row means (over w) -> xh[n][c][h], col means (over h) -> xw[n][c][w]
// Zig-zag: descending plane order within each XCD, vs k_apply's ascending —
// each pass's tail leaves the other's head L2-hot.
// k_reduce itself is pinned at the chip's per-direction beyond-L2 read rate
// (~3.15 TB/s, = m13 copy reference): ten structural variants all measured
// 42-50 us. Keep the simplest.
__global__ __launch_bounds__(256) void k_reduce(const float* __restrict__ x,
                                                const float* __restrict__ res,
                                                float* __restrict__ xh,
                                                float* __restrict__ xw) {
    int bid = blockIdx.x;
    int plane = (bid & 7) + 8 * (511 - (bid >> 3));   // same XCD as bid, reversed order
    const float4* px4 = (const float4*)(x   + (size_t)plane * 4096);
    const float4* pr4 = (const float4*)(res + (size_t)plane * 4096);
    __shared__ float spad[256];
    int t = threadIdx.x;

    float4 a[4], b[4];
#pragma unroll
    for (int i = 0; i < 4; i++) a[i] = px4[i * 256 + t];
#pragma unroll
    for (int i = 0; i < 4; i++) b[i] = pr4[i * 256 + t];

    float csum0 = 0.f, csum1 = 0.f, csum2 = 0.f, csum3 = 0.f;
    float rsum[4];
#pragma unroll
    for (int i = 0; i < 4; i++) {
        float s0 = a[i].x + b[i].x, s1 = a[i].y + b[i].y;
        float s2 = a[i].z + b[i].z, s3 = a[i].w + b[i].w;
        csum0 += s0; csum1 += s1; csum2 += s2; csum3 += s3;
        rsum[i] = (s0 + s1) + (s2 + s3);
    }
#pragma unroll
    for (int i = 0; i < 4; i++) {
        float rs = rsum[i];
        rs += __shfl_xor(rs, 1);
        rs += __shfl_xor(rs, 2);
        rs += __shfl_xor(rs, 4);
        rs += __shfl_xor(rs, 8);
        rsum[i] = rs;
    }
    if ((t & 15) == 0) {
        int g = t >> 4;
#pragma unroll
        for (int i = 0; i < 4; i++)
            xh[(size_t)plane * 64 + i * 16 + g] = rsum[i] * 0.015625f;
    }
    csum0 += __shfl_xor(csum0, 16); csum0 += __shfl_xor(csum0, 32);
    csum1 += __shfl_xor(csum1, 16); csum1 += __shfl_xor(csum1, 32);
    csum2 += __shfl_xor(csum2, 16); csum2 += __shfl_xor(csum2, 32);
    csum3 += __shfl_xor(csum3, 16); csum3 += __shfl_xor(csum3, 32);
    int wv = t >> 6;
    int j  = t & 15;
    if ((t & 63) < 16) {
        float* d = &spad[wv * 64 + j * 4];
        d[0] = csum0; d[1] = csum1; d[2] = csum2; d[3] = csum3;
    }
    __syncthreads();
    if (t < 64)
        xw[(size_t)plane * 64 + t] =
            (spad[t] + spad[64 + t] + spad[128 + t] + spad[192 + t]) * 0.015625f;
}

// K2: grid = NB*8 blocks. Block (n, pc) covers p in [pc*16, pc*16+16).
// Computes yl[m][p] for its p-range (c-split + LDS combine), then the full
// sigmoid layer at those p's, emitting ah/aw directly.
__global__ __launch_bounds__(256) void k_mid(const float* __restrict__ xh,
                                             const float* __restrict__ xw,
                                             const float* __restrict__ w1,
                                             const float* __restrict__ b1,
                                             const float* __restrict__ gamma,
                                             const float* __restrict__ beta,
                                             const float* __restrict__ mean,
                                             const float* __restrict__ var,
                                             const float* __restrict__ w2,
                                             const float* __restrict__ b2,
                                             const float* __restrict__ w3,
                                             const float* __restrict__ b3,
                                             float* __restrict__ ah,
                                             float* __restrict__ aw) {
    int n  = blockIdx.x >> 3;
    int pc = blockIdx.x & 7;
    int t  = threadIdx.x;
    int ph = t & 15;
    int p  = pc * 16 + ph;
    int m  = (t >> 4) & 7;
    int half = t >> 7;
    __shared__ float part[256];
    __shared__ float ylds[MIP * 16];

    const float* pool = (p < 64) ? (xh + ((size_t)n * CB) * 64 + p)
                                 : (xw + ((size_t)n * CB) * 64 + (p - 64));
    float acc = 0.f;
    int c0 = half * 128;
#pragma unroll 16
    for (int ci = 0; ci < 128; ci++) {
        int c = c0 + ci;
        acc += pool[(size_t)c * 64] * w1[m * CB + c];
    }
    part[t] = acc;
    __syncthreads();
    if (t < 128) {
        float val = part[t] + part[t + 128] + b1[m];
        float inv = gamma[m] * rsqrtf(var[m] + EPSV);
        val = (val - mean[m]) * inv + beta[m];
        float cl = fminf(fmaxf(val + 3.f, 0.f), 6.f);
        ylds[m * 16 + ph] = val * cl * (1.f / 6.f);
    }
    __syncthreads();

    const float* wsel = (p < 64) ? w2 : w3;
    const float* bsel = (p < 64) ? b2 : b3;
    float* osel = (p < 64) ? (ah + ((size_t)n * CB) * 64 + p)
                           : (aw + ((size_t)n * CB) * 64 + (p - 64));
#pragma unroll
    for (int oo = 0; oo < 16; oo++) {
        int o = oo * 16 + (t >> 4);
        float acc2 = bsel[o];
#pragma unroll
        for (int mm = 0; mm < MIP; mm++)
            acc2 += wsel[o * MIP + mm] * ylds[mm * 16 + ph];
        osel[(size_t)o * 64] = 1.f / (1.f + __expf(-acc2));
    }
}

// K3: per (n,o) plane: load ah/aw (precomputed), out = 2*wei*x + 2*res.
// Ascending plane order (head reads k_reduce's L2-hot tail).
__global__ __launch_bounds__(256) void k_apply(const float* __restrict__ x,
                                               const float* __restrict__ res,
                                               const float* __restrict__ ah,
                                               const float* __restrict__ aw,
                                               float* __restrict__ out) {
    int plane = blockIdx.x;                       // n*256 + o
    const float4* px4 = (const float4*)(x   + (size_t)plane * 4096);
    const float4* pr4 = (const float4*)(res + (size_t)plane * 4096);
    float4*       po4 = (float4*)(out + (size_t)plane * 4096);
    __shared__ float sah[64], saw[64];
    int t = threadIdx.x;
    if (t < 64)       sah[t]      = ah[(size_t)plane * 64 + t];
    else if (t < 128) saw[t - 64] = aw[(size_t)plane * 64 + (t - 64)];
    __syncthreads();
    const float4 sw4 = *(const float4*)&saw[4 * (t & 15)];
#pragma unroll
    for (int i = 0; i < 4; i++) {
        int row = i * 16 + (t >> 4);
        float ahr2 = 2.f * sah[row];
        float4 a = px4[i * 256 + t];
        float4 b = pr4[i * 256 + t];
        float4 oo;
        oo.x = a.x * (ahr2 * sw4.x) + 2.f * b.x;
        oo.y = a.y * (ahr2 * sw4.y) + 2.f * b.y;
        oo.z = a.z * (ahr2 * sw4.z) + 2.f * b.z;
        oo.w = a.w * (ahr2 * sw4.w) + 2.f * b.w;
        po4[i * 256 + t] = oo;
    }
}

extern "C" void kernel_launch(void* const* d_in, const int* in_sizes, int n_in,
                              void* d_out, int out_size, void* d_ws, size_t ws_size,
                              hipStream_t stream) {
    const float* x     = (const float*)d_in[0];
    const float* res   = (const float*)d_in[1];
    const float* w1    = (const float*)d_in[2];
    const float* b1    = (const float*)d_in[3];
    const float* gamma = (const float*)d_in[4];
    const float* beta  = (const float*)d_in[5];
    const float* mean  = (const float*)d_in[6];
    const float* var   = (const float*)d_in[7];
    const float* w2    = (const float*)d_in[8];
    const float* b2    = (const float*)d_in[9];
    const float* w3    = (const float*)d_in[10];
    const float* b3    = (const float*)d_in[11];
    float* out = (float*)d_out;

    float* ws = (float*)d_ws;
    float* xh = ws;                 // 16*256*64 = 262144 floats
    float* xw = ws + 262144;
    float* ah = ws + 524288;
    float* aw = ws + 786432;        // total 4 MiB

    k_reduce<<<NB * CB, 256, 0, stream>>>(x, res, xh, xw);
    k_mid<<<NB * 8, 256, 0, stream>>>(xh, xw, w1, b1, gamma, beta, mean, var,
                                      w2, b2, w3, b3, ah, aw);
    k_apply<<<NB * CB, 256, 0, stream>>>(x, res, ah, aw, out);
}